// Round 9
// baseline (102.829 us; speedup 1.0000x reference)
//
#include <hip/hip_runtime.h>
#include <stdint.h>

#define N_BOX 1024
#define NUM_CLASSES 80
#define MAX_OUT 100
#define KEPT_STRIDE 128  // ints per class (512 B) — no cross-XCD false sharing
#define WS_POISON 0xAAAAAAAAu

__device__ __forceinline__ void cas64(unsigned long long& a, unsigned long long& b, bool desc) {
    bool sw = desc ? (a < b) : (a > b);
    unsigned long long t = a;
    a = sw ? b : a;
    b = sw ? t : b;
}

// Single fused dispatch, 80 blocks (one class each), no cooperative launch.
//  - sort: hybrid register/shfl bitonic (verified R5-R8), all 4 waves
//  - greedy: wave 0, on-the-fly IoU (verified R5/R7/R8)
//  - publish: SYSTEM-scope release store of counts[c] + SYSTEM fetch_add on ready
//  - block 0: ONE lane polls ready via fetch_add(0) RMW (always coherent, never
//    stale-L2) until poison+80; other lanes zero d_out meanwhile; then scan+scatter.
__global__ __launch_bounds__(256) void nms_fused(const float* __restrict__ boxes,
                                                 const float* __restrict__ scores,
                                                 int* __restrict__ keptIdx,
                                                 unsigned int* __restrict__ counts,
                                                 unsigned int* __restrict__ ready,
                                                 int* __restrict__ out) {
    __shared__ float4 sbox[N_BOX];              // 16 KB  [y1,x1,y2,x2]
    __shared__ float sarea[N_BOX];              // 4 KB
    __shared__ unsigned long long keys[N_BOX];  // 8 KB
    __shared__ float4 kbox[MAX_OUT];            // kept boxes
    __shared__ float karea[MAX_OUT];
    __shared__ int scnt[NUM_CLASSES];
    const int c = blockIdx.x;
    const int tid = threadIdx.x;
    const int lane = tid & 63;

    for (int i = tid; i < N_BOX; i += 256) {
        float4 b = reinterpret_cast<const float4*>(boxes)[i];
        sbox[i] = b;
        sarea[i] = (b.z - b.x) * (b.w - b.y);
    }

    // Keys: (score_bits<<32) | (0xFFFFFFFF - idx); descending == stable argsort(-scores).
    const float* sc = scores + (size_t)c * N_BOX;
    float4 s4 = reinterpret_cast<const float4*>(sc)[tid];
    const int i0 = tid * 4;
    unsigned long long K[4];
    K[0] = ((unsigned long long)__float_as_uint(s4.x) << 32) | (unsigned long long)(0xFFFFFFFFu - (unsigned)(i0 + 0));
    K[1] = ((unsigned long long)__float_as_uint(s4.y) << 32) | (unsigned long long)(0xFFFFFFFFu - (unsigned)(i0 + 1));
    K[2] = ((unsigned long long)__float_as_uint(s4.z) << 32) | (unsigned long long)(0xFFFFFFFFu - (unsigned)(i0 + 2));
    K[3] = ((unsigned long long)__float_as_uint(s4.w) << 32) | (unsigned long long)(0xFFFFFFFFu - (unsigned)(i0 + 3));

    auto shfl_pass = [&](int j, bool d) {  // element-xor j>=4 -> lane-xor j/4 within wave
        int xl = j >> 2;
        bool mx = (d == ((lane & xl) == 0));
#pragma unroll
        for (int t = 0; t < 4; ++t) {
            unsigned long long p = __shfl_xor(K[t], xl, 64);
            K[t] = mx ? (K[t] >= p ? K[t] : p) : (K[t] <= p ? K[t] : p);
        }
    };
    auto thread_pass = [&](bool d) {
        cas64(K[0], K[2], d); cas64(K[1], K[3], d);
        cas64(K[0], K[1], d); cas64(K[2], K[3], d);
    };
    auto lds_pass = [&](int j, bool d) {  // cross-wave via LDS
        *reinterpret_cast<ulonglong2*>(&keys[i0])     = make_ulonglong2(K[0], K[1]);
        *reinterpret_cast<ulonglong2*>(&keys[i0 + 2]) = make_ulonglong2(K[2], K[3]);
        __syncthreads();
        int pb = i0 ^ j;
        ulonglong2 p01 = *reinterpret_cast<const ulonglong2*>(&keys[pb]);
        ulonglong2 p23 = *reinterpret_cast<const ulonglong2*>(&keys[pb + 2]);
        unsigned long long P[4] = {p01.x, p01.y, p23.x, p23.y};
        bool mx = (d == ((i0 & j) == 0));
#pragma unroll
        for (int t = 0; t < 4; ++t)
            K[t] = mx ? (K[t] >= P[t] ? K[t] : P[t]) : (K[t] <= P[t] ? K[t] : P[t]);
        __syncthreads();
    };

    cas64(K[0], K[1], true);   // k=2
    cas64(K[2], K[3], false);
    { bool d = (tid & 1) == 0; thread_pass(d); }  // k=4
    for (int k = 8; k <= 256; k <<= 1) {
        bool d = (tid & (k >> 2)) == 0;
        for (int j = k >> 1; j >= 4; j >>= 1) shfl_pass(j, d);
        thread_pass(d);
    }
    { bool d = (tid & 128) == 0;  // k=512
      lds_pass(256, d);
      for (int j = 128; j >= 4; j >>= 1) shfl_pass(j, d);
      thread_pass(d); }
    {                             // k=1024 (final, all desc)
      lds_pass(512, true); lds_pass(256, true);
      for (int j = 128; j >= 4; j >>= 1) shfl_pass(j, true);
      thread_pass(true); }
    *reinterpret_cast<ulonglong2*>(&keys[i0])     = make_ulonglong2(K[0], K[1]);
    *reinterpret_cast<ulonglong2*>(&keys[i0 + 2]) = make_ulonglong2(K[2], K[3]);
    __syncthreads();  // keys published; sbox/sarea staging complete

    // --- Greedy NMS on wave 0 (verified R5/R7/R8) ---
    if (tid < 64) {
        int kept = 0;
        int* outc = keptIdx + c * KEPT_STRIDE;
        for (int base = 0; base < N_BOX && kept < MAX_OUT; base += 64) {
            unsigned long long kk = keys[base + lane];
            unsigned int hi = (unsigned int)(kk >> 32);
            unsigned int o = 0xFFFFFFFFu - (unsigned int)kk;
            bool valid = hi > 0x3F000000u;           // score > 0.5f (nonneg floats)
            if (__ballot(valid) == 0ull) break;      // sorted: nothing left
            float4 mb = sbox[o];
            float ma = sarea[o];
            bool alive = valid;
            for (int j = 0; j < kept; ++j) {         // vs kept from earlier windows
                float4 kb = kbox[j];
                float ih = fminf(kb.z, mb.z) - fmaxf(kb.x, mb.x); ih = fmaxf(ih, 0.0f);
                float iw = fminf(kb.w, mb.w) - fmaxf(kb.y, mb.y); iw = fmaxf(iw, 0.0f);
                float inter = ih * iw;
                float uni = karea[j] + ma - inter;   // ref op order
                alive = alive && !((inter / uni) > 0.5f);
            }
            unsigned long long m = __ballot(alive);
            while (m != 0ull && kept < MAX_OUT) {
                int f = __builtin_ctzll(m);          // next survivor in sorted order
                float fx = __shfl(mb.x, f), fy = __shfl(mb.y, f);
                float fz = __shfl(mb.z, f), fw = __shfl(mb.w, f);
                float fa = __shfl(ma, f);
                unsigned int of = (unsigned int)__shfl((int)o, f);
                float ih = fminf(fz, mb.z) - fmaxf(fx, mb.x); ih = fmaxf(ih, 0.0f);
                float iw = fminf(fw, mb.w) - fmaxf(fy, mb.y); iw = fmaxf(iw, 0.0f);
                float inter = ih * iw;
                float uni = fa + ma - inter;
                bool sup = (inter / uni) > 0.5f;     // self-IoU=1 removes f itself
                if (lane == 0) {
                    outc[kept] = (int)of;
                    kbox[kept] = make_float4(fx, fy, fz, fw);
                    karea[kept] = fa;
                }
                ++kept;
                m &= ~__ballot(sup);
            }
        }
        if (lane == 0) {
            // SYSTEM scope: force count + keptIdx visibility past the local XCD L2.
            __hip_atomic_store(&counts[c], (unsigned int)kept,
                               __ATOMIC_RELEASE, __HIP_MEMORY_SCOPE_SYSTEM);
            __hip_atomic_fetch_add(ready, 1u,
                                   __ATOMIC_RELEASE, __HIP_MEMORY_SCOPE_SYSTEM);
        }
    }

    if (c != 0) return;  // blocks 1..79 done

    // --- Block 0 epilogue ---
    if (tid == 64) {
        // RMW poll: executes at the device coherence point — cannot read stale L2.
        // d_ws poison is 0xAAAAAAAA (documented, relied on in R8): target = poison+80.
        const unsigned int target = WS_POISON + (unsigned int)NUM_CLASSES;
        unsigned int v;
        do {
            v = __hip_atomic_fetch_add(ready, 0u, __ATOMIC_ACQUIRE, __HIP_MEMORY_SCOPE_SYSTEM);
        } while (v != target);
    } else if (tid >= 144) {
        int4* o4 = reinterpret_cast<int4*>(out);
        for (int i = tid - 144; i < (NUM_CLASSES * MAX_OUT * 3) / 4; i += 112)
            o4[i] = make_int4(0, 0, 0, 0);
    }
    __syncthreads();  // greedy done, ready==poison+80 observed, out zeroed

    if (tid < NUM_CLASSES)
        scnt[tid] = (int)__hip_atomic_load(&counts[tid], __ATOMIC_RELAXED,
                                           __HIP_MEMORY_SCOPE_SYSTEM);
    __syncthreads();

    // Inclusive Hillis-Steele scan over 80 counts in LDS.
    for (int d = 1; d < NUM_CLASSES; d <<= 1) {
        int v = 0;
        if (tid < NUM_CLASSES) {
            v = scnt[tid];
            if (tid >= d) v += scnt[tid - d];
        }
        __syncthreads();
        if (tid < NUM_CLASSES) scnt[tid] = v;
        __syncthreads();
    }

    // Scatter rows (0, c, idx) packed by (class, rank).
    for (int idx = tid; idx < NUM_CLASSES * MAX_OUT; idx += 256) {
        int c2 = idx / MAX_OUT;
        int r = idx - c2 * MAX_OUT;
        int excl = (c2 == 0) ? 0 : scnt[c2 - 1];
        if (r < scnt[c2] - excl) {
            int o = excl + r;
            out[o * 3 + 0] = 0;  // B == 1
            out[o * 3 + 1] = c2;
            out[o * 3 + 2] = keptIdx[c2 * KEPT_STRIDE + r];
        }
    }
}

extern "C" void kernel_launch(void* const* d_in, const int* in_sizes, int n_in,
                              void* d_out, int out_size, void* d_ws, size_t ws_size,
                              hipStream_t stream) {
    const float* boxes = (const float*)d_in[0];   // (1, 1024, 4) f32
    const float* scores = (const float*)d_in[1];  // (1, 80, 1024) f32
    int* out = (int*)d_out;                        // (8000, 3) int32

    int* keptIdx = (int*)d_ws;                                     // 80*128 ints
    unsigned int* counts = (unsigned int*)(keptIdx + NUM_CLASSES * KEPT_STRIDE);
    unsigned int* ready = counts + 128;            // own 512B-aligned region

    nms_fused<<<NUM_CLASSES, 256, 0, stream>>>(boxes, scores, keptIdx, counts, ready, out);
}

// Round 10
// 99.833 us; speedup vs baseline: 1.0300x; 1.0300x over previous
//
#include <hip/hip_runtime.h>
#include <stdint.h>

#define N_BOX 1024
#define NUM_CLASSES 80
#define MAX_OUT 100
#define KEPT_STRIDE 128  // ints per class (512 B) — no cross-XCD false sharing
#define WS_POISON 0xAAAAAAAAu

__device__ __forceinline__ void cas64(unsigned long long& a, unsigned long long& b, bool desc) {
    bool sw = desc ? (a < b) : (a > b);
    unsigned long long t = a;
    a = sw ? b : a;
    b = sw ? t : b;
}

// Single fused dispatch, 80 blocks (one class each).
// Greedy v2: per-window parallel 64x64 IoU suppression matrix (row u64 per lane),
// scalar resolution via dynamic v_readlane (~30 cyc/kept vs ~200 for bpermute chain),
// parallel kept-append via popcount self-select. Publish/poll epilogue = R9 (proven).
__global__ __launch_bounds__(256) void nms_fused(const float* __restrict__ boxes,
                                                 const float* __restrict__ scores,
                                                 int* __restrict__ keptIdx,
                                                 unsigned int* __restrict__ counts,
                                                 unsigned int* __restrict__ ready,
                                                 int* __restrict__ out) {
    __shared__ float4 sbox[N_BOX];              // 16 KB  [y1,x1,y2,x2]
    __shared__ float sarea[N_BOX];              // 4 KB
    __shared__ unsigned long long keys[N_BOX];  // 8 KB
    __shared__ float4 kbox[MAX_OUT];            // kept boxes
    __shared__ float karea[MAX_OUT];
    __shared__ int scnt[NUM_CLASSES];
    const int c = blockIdx.x;
    const int tid = threadIdx.x;
    const int lane = tid & 63;

    for (int i = tid; i < N_BOX; i += 256) {
        float4 b = reinterpret_cast<const float4*>(boxes)[i];
        sbox[i] = b;
        sarea[i] = (b.z - b.x) * (b.w - b.y);
    }

    // Keys: (score_bits<<32) | (0xFFFFFFFF - idx); descending == stable argsort(-scores).
    const float* sc = scores + (size_t)c * N_BOX;
    float4 s4 = reinterpret_cast<const float4*>(sc)[tid];
    const int i0 = tid * 4;
    unsigned long long K[4];
    K[0] = ((unsigned long long)__float_as_uint(s4.x) << 32) | (unsigned long long)(0xFFFFFFFFu - (unsigned)(i0 + 0));
    K[1] = ((unsigned long long)__float_as_uint(s4.y) << 32) | (unsigned long long)(0xFFFFFFFFu - (unsigned)(i0 + 1));
    K[2] = ((unsigned long long)__float_as_uint(s4.z) << 32) | (unsigned long long)(0xFFFFFFFFu - (unsigned)(i0 + 2));
    K[3] = ((unsigned long long)__float_as_uint(s4.w) << 32) | (unsigned long long)(0xFFFFFFFFu - (unsigned)(i0 + 3));

    auto shfl_pass = [&](int j, bool d) {  // element-xor j>=4 -> lane-xor j/4 within wave
        int xl = j >> 2;
        bool mx = (d == ((lane & xl) == 0));
#pragma unroll
        for (int t = 0; t < 4; ++t) {
            unsigned long long p = __shfl_xor(K[t], xl, 64);
            K[t] = mx ? (K[t] >= p ? K[t] : p) : (K[t] <= p ? K[t] : p);
        }
    };
    auto thread_pass = [&](bool d) {
        cas64(K[0], K[2], d); cas64(K[1], K[3], d);
        cas64(K[0], K[1], d); cas64(K[2], K[3], d);
    };
    auto lds_pass = [&](int j, bool d) {  // cross-wave via LDS
        *reinterpret_cast<ulonglong2*>(&keys[i0])     = make_ulonglong2(K[0], K[1]);
        *reinterpret_cast<ulonglong2*>(&keys[i0 + 2]) = make_ulonglong2(K[2], K[3]);
        __syncthreads();
        int pb = i0 ^ j;
        ulonglong2 p01 = *reinterpret_cast<const ulonglong2*>(&keys[pb]);
        ulonglong2 p23 = *reinterpret_cast<const ulonglong2*>(&keys[pb + 2]);
        unsigned long long P[4] = {p01.x, p01.y, p23.x, p23.y};
        bool mx = (d == ((i0 & j) == 0));
#pragma unroll
        for (int t = 0; t < 4; ++t)
            K[t] = mx ? (K[t] >= P[t] ? K[t] : P[t]) : (K[t] <= P[t] ? K[t] : P[t]);
        __syncthreads();
    };

    cas64(K[0], K[1], true);   // k=2
    cas64(K[2], K[3], false);
    { bool d = (tid & 1) == 0; thread_pass(d); }  // k=4
    for (int k = 8; k <= 256; k <<= 1) {
        bool d = (tid & (k >> 2)) == 0;
        for (int j = k >> 1; j >= 4; j >>= 1) shfl_pass(j, d);
        thread_pass(d);
    }
    { bool d = (tid & 128) == 0;  // k=512
      lds_pass(256, d);
      for (int j = 128; j >= 4; j >>= 1) shfl_pass(j, d);
      thread_pass(d); }
    {                             // k=1024 (final, all desc)
      lds_pass(512, true); lds_pass(256, true);
      for (int j = 128; j >= 4; j >>= 1) shfl_pass(j, true);
      thread_pass(true); }
    *reinterpret_cast<ulonglong2*>(&keys[i0])     = make_ulonglong2(K[0], K[1]);
    *reinterpret_cast<ulonglong2*>(&keys[i0 + 2]) = make_ulonglong2(K[2], K[3]);
    __syncthreads();  // keys published; sbox/sarea staging complete

    // --- Greedy NMS v2 on wave 0 ---
    if (tid < 64) {
        int kept = 0;
        int* outc = keptIdx + c * KEPT_STRIDE;
        for (int base = 0; base < N_BOX && kept < MAX_OUT; base += 64) {
            unsigned long long kk = keys[base + lane];
            unsigned int hi = (unsigned int)(kk >> 32);
            unsigned int o = 0xFFFFFFFFu - (unsigned int)kk;
            bool valid = hi > 0x3F000000u;           // score > 0.5f (nonneg floats)
            if (__ballot(valid) == 0ull) break;      // sorted: nothing left
            float4 mb = sbox[o];
            float ma = sarea[o];
            // Cross-window: test my candidate vs kept list (independent iters, pipelines).
            bool alive = valid;
            for (int j = 0; j < kept; ++j) {
                float4 kb = kbox[j];
                float ih = fminf(kb.z, mb.z) - fmaxf(kb.x, mb.x); ih = fmaxf(ih, 0.0f);
                float iw = fminf(kb.w, mb.w) - fmaxf(kb.y, mb.y); iw = fmaxf(iw, 0.0f);
                float inter = ih * iw;
                float uni = karea[j] + ma - inter;   // ref op order
                alive = alive && !((inter / uni) > 0.5f);
            }
            unsigned long long m = __ballot(alive);
            if (m == 0ull) continue;
            // In-window 64x64 suppression matrix, fully parallel: bit j of my row =
            // IoU(me, window-mate j) > 0.5 (symmetric; self bit = 1 since IoU=1).
            unsigned long long row = 0ull;
#pragma unroll 8
            for (int j = 0; j < 64; ++j) {
                unsigned int oj = (unsigned int)__shfl((int)o, j);  // uniform broadcast
                float4 bj = sbox[oj];                               // LDS broadcast read
                float aj = sarea[oj];
                float ih = fminf(bj.z, mb.z) - fmaxf(bj.x, mb.x); ih = fmaxf(ih, 0.0f);
                float iw = fminf(bj.w, mb.w) - fmaxf(bj.y, mb.y); iw = fmaxf(iw, 0.0f);
                float inter = ih * iw;
                float uni = aj + ma - inter;
                if ((inter / uni) > 0.5f) row |= 1ull << j;
            }
            // Scalar resolution: per kept box ~ ctz + 2 dynamic v_readlane + andn2.
            unsigned long long Km = 0ull;
            int kept0 = kept;
            while (m != 0ull && kept < MAX_OUT) {
                int f = __builtin_ctzll(m);          // lowest lane = best score (bits<f clear)
                Km |= 1ull << f;
                ++kept;
                unsigned int rlo = (unsigned int)__builtin_amdgcn_readlane((int)(unsigned int)row, f);
                unsigned int rhi = (unsigned int)__builtin_amdgcn_readlane((int)(unsigned int)(row >> 32), f);
                unsigned long long rowf = ((unsigned long long)rhi << 32) | rlo;
                m &= ~rowf;                          // clears f (self-bit) + all it suppresses
            }
            // Parallel append of this window's kept boxes in sorted (lane) order.
            if ((Km >> lane) & 1ull) {
                int pos = kept0 + __popcll(Km & ((1ull << lane) - 1ull));
                outc[pos] = (int)o;
                kbox[pos] = mb;
                karea[pos] = ma;
            }
        }
        if (lane == 0) {
            __hip_atomic_store(&counts[c], (unsigned int)kept,
                               __ATOMIC_RELEASE, __HIP_MEMORY_SCOPE_SYSTEM);
            __hip_atomic_fetch_add(ready, 1u,
                                   __ATOMIC_RELEASE, __HIP_MEMORY_SCOPE_SYSTEM);
        }
    }

    if (c != 0) return;  // blocks 1..79 done

    // --- Block 0 epilogue (R9-proven) ---
    if (tid == 64) {
        // RMW poll at the coherence point — cannot read stale L2. Poison target:
        const unsigned int target = WS_POISON + (unsigned int)NUM_CLASSES;
        unsigned int v;
        do {
            v = __hip_atomic_fetch_add(ready, 0u, __ATOMIC_ACQUIRE, __HIP_MEMORY_SCOPE_SYSTEM);
        } while (v != target);
    } else if (tid >= 144) {
        int4* o4 = reinterpret_cast<int4*>(out);
        for (int i = tid - 144; i < (NUM_CLASSES * MAX_OUT * 3) / 4; i += 112)
            o4[i] = make_int4(0, 0, 0, 0);
    }
    __syncthreads();  // greedy done, all 80 publishes observed, out zeroed

    if (tid < NUM_CLASSES)
        scnt[tid] = (int)__hip_atomic_load(&counts[tid], __ATOMIC_RELAXED,
                                           __HIP_MEMORY_SCOPE_SYSTEM);
    __syncthreads();

    // Inclusive Hillis-Steele scan over 80 counts in LDS.
    for (int d = 1; d < NUM_CLASSES; d <<= 1) {
        int v = 0;
        if (tid < NUM_CLASSES) {
            v = scnt[tid];
            if (tid >= d) v += scnt[tid - d];
        }
        __syncthreads();
        if (tid < NUM_CLASSES) scnt[tid] = v;
        __syncthreads();
    }

    // Scatter rows (0, c, idx) packed by (class, rank).
    for (int idx = tid; idx < NUM_CLASSES * MAX_OUT; idx += 256) {
        int c2 = idx / MAX_OUT;
        int r = idx - c2 * MAX_OUT;
        int excl = (c2 == 0) ? 0 : scnt[c2 - 1];
        if (r < scnt[c2] - excl) {
            int o = excl + r;
            out[o * 3 + 0] = 0;  // B == 1
            out[o * 3 + 1] = c2;
            out[o * 3 + 2] = keptIdx[c2 * KEPT_STRIDE + r];
        }
    }
}

extern "C" void kernel_launch(void* const* d_in, const int* in_sizes, int n_in,
                              void* d_out, int out_size, void* d_ws, size_t ws_size,
                              hipStream_t stream) {
    const float* boxes = (const float*)d_in[0];   // (1, 1024, 4) f32
    const float* scores = (const float*)d_in[1];  // (1, 80, 1024) f32
    int* out = (int*)d_out;                        // (8000, 3) int32

    int* keptIdx = (int*)d_ws;                                     // 80*128 ints
    unsigned int* counts = (unsigned int*)(keptIdx + NUM_CLASSES * KEPT_STRIDE);
    unsigned int* ready = counts + 128;            // own 512B-aligned region

    nms_fused<<<NUM_CLASSES, 256, 0, stream>>>(boxes, scores, keptIdx, counts, ready, out);
}